// Round 1
// baseline (1154.262 us; speedup 1.0000x reference)
//
#include <hip/hip_runtime.h>
#include <hip/hip_bf16.h>
#include <stdint.h>

#define DD 32
#define KH 96   // 3*D

// ws layout:
//  hdr (uint32):
//   [0] idx_mode  (0 = int64, 1 = int32)
//   [1] sel_mode  (0 = int64, 1 = int32, 2 = bytes)
//   [2] fmode     (0 = bf16 floats, 1 = fp32 floats)
//   [3] min_key   (encoded float, atomicMin over ALL state_prob)
//   [4] max_key   (encoded float, atomicMax over UNSELECTED state_prob)
//   [5] cnt_unsel
//   [6] sum       (float bits, atomicAdd)
//  ws+256    : float Wf[3072]
//  ws+12544  : float bf[32]
//  ws+12672  : float vf[32]   (graph_rep - subgraph_rep)
//  ws+16384  : float sp[E]

__device__ __forceinline__ uint32_t fkey(float f) {
    uint32_t b = __float_as_uint(f);
    return (b & 0x80000000u) ? ~b : (b | 0x80000000u);
}
__device__ __forceinline__ float funkey(uint32_t k) {
    uint32_t b = (k & 0x80000000u) ? (k & 0x7FFFFFFFu) : ~k;
    return __uint_as_float(b);
}
__device__ __forceinline__ float bflo(uint32_t w) { return __uint_as_float(w << 16); }
__device__ __forceinline__ float bfhi(uint32_t w) { return __uint_as_float(w & 0xFFFF0000u); }

__global__ void k_init(const void* W, const void* bias, const void* g, const void* sg,
                       const void* ei, const void* sel,
                       uint32_t* hdr, float* Wf, float* bf, float* vf, int E, int N) {
    int t = threadIdx.x;
    __shared__ int sh_i32, sh_gt1, sh_odd, sh_f32;
    if (t == 0) { sh_i32 = 0; sh_gt1 = 0; sh_odd = 0; sh_f32 = 0; }
    __syncthreads();

    // float-mode detect: read W as bf16; fp32 data yields wild-exponent halves
    const uint16_t* wb = (const uint16_t*)W;
    for (int i = t; i < KH * DD; i += 256) {
        float x = bflo((uint32_t)wb[i]);
        if (!(fabsf(x) < 1e4f)) sh_f32 = 1;  // also catches inf/nan
    }
    // edge_index layout detect: int32 data read as int64 -> huge values
    const long long* ell = (const long long*)ei;
    int ns = 2048 < E ? 2048 : E;
    for (int i = t; i < ns; i += 256) {
        long long v = ell[i];
        if (v < 0 || v >= (long long)N) sh_i32 = 1;
    }
    // selection layout detect
    const uint32_t* sw = (const uint32_t*)sel;
    int ns2 = 2048 < E / 4 ? 2048 : E / 4;
    for (int i = t; i < ns2; i += 256) {
        uint32_t v = sw[i];
        if (v > 1u) sh_gt1 = 1;             // packed bytes
        if (v != 0u && (i & 1)) sh_odd = 1; // int32 (int64 has all odd words zero)
    }
    __syncthreads();
    int fmode = sh_f32;

    // convert params to fp32 in ws
    for (int i = t; i < KH * DD; i += 256)
        Wf[i] = fmode ? ((const float*)W)[i] : bflo((uint32_t)wb[i]);
    for (int i = t; i < DD; i += 256) {
        bf[i] = fmode ? ((const float*)bias)[i] : bflo((uint32_t)((const uint16_t*)bias)[i]);
        float gv = fmode ? ((const float*)g)[i]  : bflo((uint32_t)((const uint16_t*)g)[i]);
        float sv = fmode ? ((const float*)sg)[i] : bflo((uint32_t)((const uint16_t*)sg)[i]);
        vf[i] = gv - sv;
    }
    if (t == 0) {
        hdr[0] = (uint32_t)sh_i32;
        hdr[1] = sh_gt1 ? 2u : (sh_odd ? 1u : 0u);
        hdr[2] = (uint32_t)fmode;
        hdr[3] = 0xFFFFFFFFu;  // min key init (+inf-ish)
        hdr[4] = 0u;           // max key init (-inf-ish)
        hdr[5] = 0u;
        hdr[6] = 0u;           // float 0.0
    }
}

__device__ __forceinline__ void load_row(const void* base, size_t row, int fmode, float* h) {
    if (fmode) {
        const float4* q = (const float4*)((const float*)base + row * DD);
        #pragma unroll
        for (int t = 0; t < 8; ++t) {
            float4 u = q[t];
            h[t * 4 + 0] = u.x; h[t * 4 + 1] = u.y; h[t * 4 + 2] = u.z; h[t * 4 + 3] = u.w;
        }
    } else {
        const uint4* q = (const uint4*)((const uint16_t*)base + row * DD);
        #pragma unroll
        for (int t = 0; t < 4; ++t) {
            uint4 u = q[t];
            uint32_t w0 = u.x, w1 = u.y, w2 = u.z, w3 = u.w;
            h[t * 8 + 0] = bflo(w0); h[t * 8 + 1] = bfhi(w0);
            h[t * 8 + 2] = bflo(w1); h[t * 8 + 3] = bfhi(w1);
            h[t * 8 + 4] = bflo(w2); h[t * 8 + 5] = bfhi(w2);
            h[t * 8 + 6] = bflo(w3); h[t * 8 + 7] = bfhi(w3);
        }
    }
}

__device__ __forceinline__ bool fetch_sel(const void* sel, int mode, int e) {
    if (mode == 2) return ((const uint8_t*)sel)[e] != 0;
    if (mode == 1) return ((const int*)sel)[e] != 0;
    return ((const long long*)sel)[e] != 0;
}

__device__ __forceinline__ float compute_sp(int e, const void* node, const void* edge,
                                            const void* ei, int idx_mode, int fmode,
                                            const float* Wf, const float* bf, const float* vf,
                                            int E, int N) {
    long long si, di;
    if (idx_mode) { si = ((const int*)ei)[e]; di = ((const int*)ei)[E + e]; }
    else          { si = ((const long long*)ei)[e]; di = ((const long long*)ei)[E + e]; }
    int s0 = (int)si, d0 = (int)di;
    s0 = s0 < 0 ? 0 : (s0 >= N ? N - 1 : s0);
    d0 = d0 < 0 ? 0 : (d0 >= N ? N - 1 : d0);

    float h[KH];
    load_row(node, (size_t)s0, fmode, h);
    load_row(node, (size_t)d0, fmode, h + 32);
    load_row(edge, (size_t)e, fmode, h + 64);

    float sp = 0.f;
    for (int j = 0; j < DD; ++j) {
        float a0 = bf[j], a1 = 0.f, a2 = 0.f, a3 = 0.f;
        #pragma unroll
        for (int k = 0; k < KH; k += 4) {
            a0 = fmaf(h[k + 0], Wf[(k + 0) * DD + j], a0);
            a1 = fmaf(h[k + 1], Wf[(k + 1) * DD + j], a1);
            a2 = fmaf(h[k + 2], Wf[(k + 2) * DD + j], a2);
            a3 = fmaf(h[k + 3], Wf[(k + 3) * DD + j], a3);
        }
        float acc = (a0 + a1) + (a2 + a3);
        float act = acc > 0.f ? acc : (__expf(acc) - 1.f);
        sp = fmaf(act, vf[j], sp);
    }
    return sp;
}

template <int STORE>
__global__ __launch_bounds__(256) void k_pass1(const void* node, const void* edge, const void* ei,
                                               const void* sel, uint32_t* hdr, const float* Wf,
                                               const float* bf, const float* vf, float* sp_arr,
                                               int E, int N) {
    int e = blockIdx.x * 256 + threadIdx.x;
    int idx_mode = (int)hdr[0], sel_mode = (int)hdr[1], fmode = (int)hdr[2];
    float sp = 0.f;
    bool selv = true;
    bool valid = e < E;
    if (valid) {
        sp = compute_sp(e, node, edge, ei, idx_mode, fmode, Wf, bf, vf, E, N);
        if (STORE) sp_arr[e] = sp;
        selv = fetch_sel(sel, sel_mode, e);
    }
    float mn = valid ? sp : __builtin_inff();
    float mx = (valid && !selv) ? sp : -__builtin_inff();
    uint32_t c = (valid && !selv) ? 1u : 0u;
    #pragma unroll
    for (int o = 32; o >= 1; o >>= 1) {
        mn = fminf(mn, __shfl_xor(mn, o));
        mx = fmaxf(mx, __shfl_xor(mx, o));
        c += __shfl_xor(c, o);
    }
    __shared__ float smn[4], smx[4];
    __shared__ uint32_t sc[4];
    int wid = threadIdx.x >> 6, lane = threadIdx.x & 63;
    if (lane == 0) { smn[wid] = mn; smx[wid] = mx; sc[wid] = c; }
    __syncthreads();
    if (threadIdx.x == 0) {
        for (int w = 1; w < 4; ++w) { mn = fminf(mn, smn[w]); mx = fmaxf(mx, smx[w]); c += sc[w]; }
        atomicMin(&hdr[3], fkey(mn));
        atomicMax(&hdr[4], fkey(mx));
        if (c) atomicAdd(&hdr[5], c);
    }
}

template <int LOAD>
__global__ __launch_bounds__(256) void k_pass2(const void* node, const void* edge, const void* ei,
                                               const void* sel, uint32_t* hdr, const float* Wf,
                                               const float* bf, const float* vf,
                                               const float* sp_arr, int E, int N) {
    int e = blockIdx.x * 256 + threadIdx.x;
    int idx_mode = (int)hdr[0], sel_mode = (int)hdr[1], fmode = (int)hdr[2];
    float mn = funkey(hdr[3]);
    uint32_t cnt = hdr[5];
    float M = cnt ? funkey(hdr[4]) : mn;
    float p = 0.f;
    if (e < E) {
        float sp = LOAD ? sp_arr[e]
                        : compute_sp(e, node, edge, ei, idx_mode, fmode, Wf, bf, vf, E, N);
        bool selv = fetch_sel(sel, sel_mode, e);
        float masked = selv ? mn : sp;
        p = __expf((masked - M) * 2.0f);  // 1/T = 2
    }
    #pragma unroll
    for (int o = 32; o >= 1; o >>= 1) p += __shfl_xor(p, o);
    __shared__ float sps[4];
    int wid = threadIdx.x >> 6, lane = threadIdx.x & 63;
    if (lane == 0) sps[wid] = p;
    __syncthreads();
    if (threadIdx.x == 0) {
        p += sps[1] + sps[2] + sps[3];
        atomicAdd((float*)&hdr[6], p);
    }
}

template <int LOAD>
__global__ __launch_bounds__(256) void k_pass3(const void* node, const void* edge, const void* ei,
                                               const void* sel, const uint32_t* hdr, const float* Wf,
                                               const float* bf, const float* vf,
                                               const float* sp_arr, void* out, int E, int N) {
    int e = blockIdx.x * 256 + threadIdx.x;
    if (e >= E) return;
    int idx_mode = (int)hdr[0], sel_mode = (int)hdr[1], fmode = (int)hdr[2];
    float mn = funkey(hdr[3]);
    uint32_t cnt = hdr[5];
    float M = cnt ? funkey(hdr[4]) : mn;
    float S = __uint_as_float(hdr[6]);
    float sp = LOAD ? sp_arr[e]
                    : compute_sp(e, node, edge, ei, idx_mode, fmode, Wf, bf, vf, E, N);
    bool selv = fetch_sel(sel, sel_mode, e);
    float masked = selv ? mn : sp;
    float r = __expf((masked - M) * 2.0f) / S;
    if (fmode) ((float*)out)[e] = r;
    else       ((__hip_bfloat16*)out)[e] = __float2bfloat16(r);
}

extern "C" void kernel_launch(void* const* d_in, const int* in_sizes, int n_in,
                              void* d_out, int out_size, void* d_ws, size_t ws_size,
                              hipStream_t stream) {
    int N = in_sizes[0] / DD;
    int E = in_sizes[1] / DD;
    const void* node = d_in[0];
    const void* edge = d_in[1];
    const void* g    = d_in[2];
    const void* sg   = d_in[3];
    const void* W    = d_in[4];
    const void* bias = d_in[5];
    const void* ei   = d_in[6];
    const void* sel  = d_in[7];

    uint8_t* ws = (uint8_t*)d_ws;
    uint32_t* hdr = (uint32_t*)ws;
    float* Wf = (float*)(ws + 256);
    float* bf = (float*)(ws + 256 + 12288);
    float* vf = (float*)(ws + 256 + 12288 + 128);
    float* sp_arr = (float*)(ws + 16384);
    bool store = ws_size >= (size_t)16384 + (size_t)E * sizeof(float);

    int grid = (E + 255) / 256;
    k_init<<<1, 256, 0, stream>>>(W, bias, g, sg, ei, sel, hdr, Wf, bf, vf, E, N);
    if (store) {
        k_pass1<1><<<grid, 256, 0, stream>>>(node, edge, ei, sel, hdr, Wf, bf, vf, sp_arr, E, N);
        k_pass2<1><<<grid, 256, 0, stream>>>(node, edge, ei, sel, hdr, Wf, bf, vf, sp_arr, E, N);
        k_pass3<1><<<grid, 256, 0, stream>>>(node, edge, ei, sel, hdr, Wf, bf, vf, sp_arr, d_out, E, N);
    } else {
        k_pass1<0><<<grid, 256, 0, stream>>>(node, edge, ei, sel, hdr, Wf, bf, vf, sp_arr, E, N);
        k_pass2<0><<<grid, 256, 0, stream>>>(node, edge, ei, sel, hdr, Wf, bf, vf, sp_arr, E, N);
        k_pass3<0><<<grid, 256, 0, stream>>>(node, edge, ei, sel, hdr, Wf, bf, vf, sp_arr, d_out, E, N);
    }
}

// Round 2
// 1142.012 us; speedup vs baseline: 1.0107x; 1.0107x over previous
//
#include <hip/hip_runtime.h>
#include <hip/hip_bf16.h>
#include <stdint.h>

#define DD 32
#define KH 96   // 3*D

// ws layout:
//  hdr (uint32):
//   [0] idx_mode  (0 = int64, 1 = int32)
//   [1] sel_mode  (0 = int64, 1 = int32, 2 = bytes)
//   [2] fmode     (0 = bf16 floats, 1 = fp32 floats)
//   [3] min_key   (encoded float, atomicMin over ALL state_prob)
//   [4] max_key   (encoded float, atomicMax over UNSELECTED state_prob)
//   [5] cnt_unsel
//   [6] sum       (float bits, atomicAdd)
//  ws+256    : float Wf[3072]
//  ws+12544  : float bf[32]
//  ws+12672  : float vf[32]
//  ws+16384  : float sp[E]   (only if ws_size permits; else sp lives in d_out)

__device__ __forceinline__ uint32_t fkey(float f) {
    uint32_t b = __float_as_uint(f);
    return (b & 0x80000000u) ? ~b : (b | 0x80000000u);
}
__device__ __forceinline__ float funkey(uint32_t k) {
    uint32_t b = (k & 0x80000000u) ? (k & 0x7FFFFFFFu) : ~k;
    return __uint_as_float(b);
}
__device__ __forceinline__ float bflo(uint32_t w) { return __uint_as_float(w << 16); }
__device__ __forceinline__ float bfhi(uint32_t w) { return __uint_as_float(w & 0xFFFF0000u); }
__device__ __forceinline__ uint16_t f2bf(float v) {
    uint32_t u = __float_as_uint(v);
    uint32_t r = (u + 0x7FFFu + ((u >> 16) & 1u)) >> 16;
    return (uint16_t)r;
}

__global__ void k_init(const void* W, const void* bias, const void* g, const void* sg,
                       const void* ei, const void* sel,
                       uint32_t* hdr, float* Wf, float* bf, float* vf, int E, int N) {
    int t = threadIdx.x;
    __shared__ int sh_i32, sh_gt1, sh_odd, sh_f32;
    if (t == 0) { sh_i32 = 0; sh_gt1 = 0; sh_odd = 0; sh_f32 = 0; }
    __syncthreads();

    const uint16_t* wb = (const uint16_t*)W;
    for (int i = t; i < KH * DD; i += 256) {
        float x = bflo((uint32_t)wb[i]);
        if (!(fabsf(x) < 1e4f)) sh_f32 = 1;
    }
    const long long* ell = (const long long*)ei;
    int ns = 2048 < E ? 2048 : E;
    for (int i = t; i < ns; i += 256) {
        long long v = ell[i];
        if (v < 0 || v >= (long long)N) sh_i32 = 1;
    }
    const uint32_t* sw = (const uint32_t*)sel;
    int ns2 = 2048 < E / 4 ? 2048 : E / 4;
    for (int i = t; i < ns2; i += 256) {
        uint32_t v = sw[i];
        if (v > 1u) sh_gt1 = 1;
        if (v != 0u && (i & 1)) sh_odd = 1;
    }
    __syncthreads();
    int fmode = sh_f32;

    for (int i = t; i < KH * DD; i += 256)
        Wf[i] = fmode ? ((const float*)W)[i] : bflo((uint32_t)wb[i]);
    for (int i = t; i < DD; i += 256) {
        bf[i] = fmode ? ((const float*)bias)[i] : bflo((uint32_t)((const uint16_t*)bias)[i]);
        float gv = fmode ? ((const float*)g)[i]  : bflo((uint32_t)((const uint16_t*)g)[i]);
        float sv = fmode ? ((const float*)sg)[i] : bflo((uint32_t)((const uint16_t*)sg)[i]);
        vf[i] = gv - sv;
    }
    if (t == 0) {
        hdr[0] = (uint32_t)sh_i32;
        hdr[1] = sh_gt1 ? 2u : (sh_odd ? 1u : 0u);
        hdr[2] = (uint32_t)fmode;
        hdr[3] = 0xFFFFFFFFu;
        hdr[4] = 0u;
        hdr[5] = 0u;
        hdr[6] = 0u;
    }
}

__device__ __forceinline__ void loadrow(const char* __restrict__ p, int fmode, float* h) {
    if (fmode) {
        const float4* q = (const float4*)p;
        #pragma unroll
        for (int t = 0; t < 8; ++t) {
            float4 u = q[t];
            h[t * 4 + 0] = u.x; h[t * 4 + 1] = u.y; h[t * 4 + 2] = u.z; h[t * 4 + 3] = u.w;
        }
    } else {
        const uint4* q = (const uint4*)p;
        #pragma unroll
        for (int t = 0; t < 4; ++t) {
            uint4 u = q[t];
            h[t * 8 + 0] = bflo(u.x); h[t * 8 + 1] = bfhi(u.x);
            h[t * 8 + 2] = bflo(u.y); h[t * 8 + 3] = bfhi(u.y);
            h[t * 8 + 4] = bflo(u.z); h[t * 8 + 5] = bfhi(u.z);
            h[t * 8 + 6] = bflo(u.w); h[t * 8 + 7] = bfhi(u.w);
        }
    }
}

__device__ __forceinline__ bool fetch_sel(const char* sel, int mode, int e) {
    if (mode == 2) return ((const uint8_t*)sel)[e] != 0;
    if (mode == 1) return ((const int*)sel)[e] != 0;
    return ((const long long*)sel)[e] != 0;
}

__device__ __forceinline__ void sp_store(float* __restrict__ ws_sp, void* __restrict__ out,
                                         int use_ws, int fmode, int e, float v) {
    if (use_ws) ws_sp[e] = v;
    else if (fmode) ((float*)out)[e] = v;
    else ((uint16_t*)out)[e] = f2bf(v);
}
__device__ __forceinline__ float sp_load(const float* __restrict__ ws_sp, const void* __restrict__ out,
                                         int use_ws, int fmode, int e) {
    if (use_ws) return ws_sp[e];
    if (fmode) return ((const float*)out)[e];
    return bflo((uint32_t)((const uint16_t*)out)[e]);
}

__global__ __launch_bounds__(256) void k_pass1(
    const char* __restrict__ node, const char* __restrict__ edgep,
    const char* __restrict__ ei, const char* __restrict__ sel,
    uint32_t* __restrict__ hdr, const float* __restrict__ Wf,
    const float* __restrict__ bf, const float* __restrict__ vf,
    float* __restrict__ ws_sp, void* __restrict__ out,
    int use_ws, int E, int N) {
    __shared__ __align__(16) float Ws[KH * DD];
    __shared__ float bs[DD], vs[DD];
    for (int i = threadIdx.x; i < KH * DD; i += 256) Ws[i] = Wf[i];
    if (threadIdx.x < DD) { bs[threadIdx.x] = bf[threadIdx.x]; vs[threadIdx.x] = vf[threadIdx.x]; }
    const int idx_mode = (int)hdr[0];
    const int sel_mode = (int)hdr[1];
    const int fmode    = (int)hdr[2];
    __syncthreads();

    int e = blockIdx.x * 256 + threadIdx.x;
    bool valid = e < E;
    int ec = valid ? e : E - 1;

    long long si, di;
    if (idx_mode) { si = ((const int*)ei)[ec]; di = ((const int*)ei)[E + ec]; }
    else          { si = ((const long long*)ei)[ec]; di = ((const long long*)ei)[(size_t)E + ec]; }
    int s0 = (int)si; s0 = s0 < 0 ? 0 : (s0 >= N ? N - 1 : s0);
    int d0 = (int)di; d0 = d0 < 0 ? 0 : (d0 >= N ? N - 1 : d0);

    size_t rb = fmode ? 128 : 64;
    const char* p0 = node  + (size_t)s0 * rb;
    const char* p1 = node  + (size_t)d0 * rb;
    const char* p2 = edgep + (size_t)ec * rb;

    float acc[DD];
    #pragma unroll
    for (int j = 0; j < DD; ++j) acc[j] = bs[j];

    float hh[32], hn[32];
    loadrow(p0, fmode, hh);

    #pragma unroll 1
    for (int r = 0; r < 3; ++r) {
        if (r < 2) {
            const char* pn = (r == 0) ? p1 : p2;
            loadrow(pn, fmode, hn);
        }
        const float* wb = &Ws[r * 32 * DD];
        #pragma unroll
        for (int k = 0; k < 32; ++k) {
            float hk = hh[k];
            const float4* wp = (const float4*)(wb + k * DD);
            #pragma unroll
            for (int j4 = 0; j4 < 8; ++j4) {
                float4 w = wp[j4];
                acc[j4 * 4 + 0] = fmaf(hk, w.x, acc[j4 * 4 + 0]);
                acc[j4 * 4 + 1] = fmaf(hk, w.y, acc[j4 * 4 + 1]);
                acc[j4 * 4 + 2] = fmaf(hk, w.z, acc[j4 * 4 + 2]);
                acc[j4 * 4 + 3] = fmaf(hk, w.w, acc[j4 * 4 + 3]);
            }
        }
        if (r < 2) {
            #pragma unroll
            for (int k = 0; k < 32; ++k) hh[k] = hn[k];
        }
    }

    float sp = 0.f;
    #pragma unroll
    for (int j = 0; j < DD; ++j) {
        float a = acc[j];
        float act = a > 0.f ? a : (__expf(a) - 1.f);
        sp = fmaf(act, vs[j], sp);
    }

    bool selv = true;
    if (valid) {
        sp_store(ws_sp, out, use_ws, fmode, e, sp);
        selv = fetch_sel(sel, sel_mode, e);
    }

    float mn = valid ? sp : __builtin_inff();
    float mx = (valid && !selv) ? sp : -__builtin_inff();
    uint32_t c = (valid && !selv) ? 1u : 0u;
    #pragma unroll
    for (int o = 32; o >= 1; o >>= 1) {
        mn = fminf(mn, __shfl_xor(mn, o));
        mx = fmaxf(mx, __shfl_xor(mx, o));
        c += __shfl_xor(c, o);
    }
    __shared__ float smn[4], smx[4];
    __shared__ uint32_t sc[4];
    int wid = threadIdx.x >> 6, lane = threadIdx.x & 63;
    if (lane == 0) { smn[wid] = mn; smx[wid] = mx; sc[wid] = c; }
    __syncthreads();
    if (threadIdx.x == 0) {
        for (int w = 1; w < 4; ++w) { mn = fminf(mn, smn[w]); mx = fmaxf(mx, smx[w]); c += sc[w]; }
        atomicMin(&hdr[3], fkey(mn));
        atomicMax(&hdr[4], fkey(mx));
        if (c) atomicAdd(&hdr[5], c);
    }
}

__global__ __launch_bounds__(256) void k_pass2(
    const char* __restrict__ sel, uint32_t* __restrict__ hdr,
    const float* __restrict__ ws_sp, const void* __restrict__ out,
    int use_ws, int E) {
    int e = blockIdx.x * 256 + threadIdx.x;
    int sel_mode = (int)hdr[1], fmode = (int)hdr[2];
    float mn = funkey(hdr[3]);
    uint32_t cnt = hdr[5];
    float M = cnt ? funkey(hdr[4]) : mn;
    float p = 0.f;
    if (e < E) {
        float sp = sp_load(ws_sp, out, use_ws, fmode, e);
        bool selv = fetch_sel(sel, sel_mode, e);
        float masked = selv ? mn : sp;
        p = __expf((masked - M) * 2.0f);
    }
    #pragma unroll
    for (int o = 32; o >= 1; o >>= 1) p += __shfl_xor(p, o);
    __shared__ float sps[4];
    int wid = threadIdx.x >> 6, lane = threadIdx.x & 63;
    if (lane == 0) sps[wid] = p;
    __syncthreads();
    if (threadIdx.x == 0) {
        p += sps[1] + sps[2] + sps[3];
        atomicAdd((float*)&hdr[6], p);
    }
}

__global__ __launch_bounds__(256) void k_pass3(
    const char* __restrict__ sel, const uint32_t* __restrict__ hdr,
    const float* __restrict__ ws_sp, void* __restrict__ out,
    int use_ws, int E) {
    int e = blockIdx.x * 256 + threadIdx.x;
    if (e >= E) return;
    int sel_mode = (int)hdr[1], fmode = (int)hdr[2];
    float mn = funkey(hdr[3]);
    uint32_t cnt = hdr[5];
    float M = cnt ? funkey(hdr[4]) : mn;
    float S = __uint_as_float(hdr[6]);
    float sp = sp_load(ws_sp, out, use_ws, fmode, e);
    bool selv = fetch_sel(sel, sel_mode, e);
    float masked = selv ? mn : sp;
    float r = __expf((masked - M) * 2.0f) / S;
    if (fmode) ((float*)out)[e] = r;
    else       ((uint16_t*)out)[e] = f2bf(r);
}

extern "C" void kernel_launch(void* const* d_in, const int* in_sizes, int n_in,
                              void* d_out, int out_size, void* d_ws, size_t ws_size,
                              hipStream_t stream) {
    int N = in_sizes[0] / DD;
    int E = in_sizes[1] / DD;
    const void* node = d_in[0];
    const void* edge = d_in[1];
    const void* g    = d_in[2];
    const void* sg   = d_in[3];
    const void* W    = d_in[4];
    const void* bias = d_in[5];
    const void* ei   = d_in[6];
    const void* sel  = d_in[7];

    uint8_t* ws = (uint8_t*)d_ws;
    uint32_t* hdr = (uint32_t*)ws;
    float* Wf = (float*)(ws + 256);
    float* bf = (float*)(ws + 256 + 12288);
    float* vf = (float*)(ws + 256 + 12288 + 128);
    float* sp_arr = (float*)(ws + 16384);
    int use_ws = (ws_size >= (size_t)16384 + (size_t)E * sizeof(float)) ? 1 : 0;

    int grid = (E + 255) / 256;
    k_init<<<1, 256, 0, stream>>>(W, bias, g, sg, ei, sel, hdr, Wf, bf, vf, E, N);
    k_pass1<<<grid, 256, 0, stream>>>((const char*)node, (const char*)edge, (const char*)ei,
                                      (const char*)sel, hdr, Wf, bf, vf, sp_arr, d_out,
                                      use_ws, E, N);
    k_pass2<<<grid, 256, 0, stream>>>((const char*)sel, hdr, sp_arr, d_out, use_ws, E);
    k_pass3<<<grid, 256, 0, stream>>>((const char*)sel, hdr, sp_arr, d_out, use_ws, E);
}

// Round 3
// 1126.237 us; speedup vs baseline: 1.0249x; 1.0140x over previous
//
#include <hip/hip_runtime.h>
#include <hip/hip_bf16.h>
#include <stdint.h>

#define DD 32
#define KH 96   // 3*D

// ws layout:
//  hdr (uint32):
//   [0] idx_mode  (0 = int64, 1 = int32)
//   [1] sel_mode  (0 = int64, 1 = int32, 2 = bytes)
//   [2] fmode     (0 = bf16 floats, 1 = fp32 floats)
//   [3] min_key   (encoded float, atomicMin over ALL state_prob)
//   [4] max_key   (encoded float, atomicMax over UNSELECTED state_prob)
//   [5] cnt_unsel
//   [6] sum       (float bits, atomicAdd)
//  ws+256    : float Wf[3072]
//  ws+12544  : float bf[32]
//  ws+12672  : float vf[32]
//  ws+16384  : float sp[E]   (only if ws_size permits; else sp lives in d_out)

typedef __attribute__((ext_vector_type(16))) float vf16;

__device__ __forceinline__ uint32_t fkey(float f) {
    uint32_t b = __float_as_uint(f);
    return (b & 0x80000000u) ? ~b : (b | 0x80000000u);
}
__device__ __forceinline__ float funkey(uint32_t k) {
    uint32_t b = (k & 0x80000000u) ? (k & 0x7FFFFFFFu) : ~k;
    return __uint_as_float(b);
}
__device__ __forceinline__ float bflo(uint32_t w) { return __uint_as_float(w << 16); }
__device__ __forceinline__ float bfhi(uint32_t w) { return __uint_as_float(w & 0xFFFF0000u); }
__device__ __forceinline__ uint16_t f2bf(float v) {
    uint32_t u = __float_as_uint(v);
    uint32_t r = (u + 0x7FFFu + ((u >> 16) & 1u)) >> 16;
    return (uint16_t)r;
}

// wave-uniform scalar load of 32 consecutive floats into SGPRs
__device__ __forceinline__ void wload(const float* p, vf16& a, vf16& b) {
    asm volatile("s_load_dwordx16 %0, %2, 0x0\n\t"
                 "s_load_dwordx16 %1, %2, 0x40\n\t"
                 "s_waitcnt lgkmcnt(0)"
                 : "=&s"(a), "=&s"(b)
                 : "s"(p));
}

__global__ void k_init(const void* W, const void* bias, const void* g, const void* sg,
                       const void* ei, const void* sel,
                       uint32_t* hdr, float* Wf, float* bf, float* vf, int E, int N) {
    int t = threadIdx.x;
    __shared__ int sh_i32, sh_gt1, sh_odd, sh_f32;
    if (t == 0) { sh_i32 = 0; sh_gt1 = 0; sh_odd = 0; sh_f32 = 0; }
    __syncthreads();

    const uint16_t* wb = (const uint16_t*)W;
    for (int i = t; i < KH * DD; i += 256) {
        float x = bflo((uint32_t)wb[i]);
        if (!(fabsf(x) < 1e4f)) sh_f32 = 1;
    }
    const long long* ell = (const long long*)ei;
    int ns = 2048 < E ? 2048 : E;
    for (int i = t; i < ns; i += 256) {
        long long v = ell[i];
        if (v < 0 || v >= (long long)N) sh_i32 = 1;
    }
    const uint32_t* sw = (const uint32_t*)sel;
    int ns2 = 2048 < E / 4 ? 2048 : E / 4;
    for (int i = t; i < ns2; i += 256) {
        uint32_t v = sw[i];
        if (v > 1u) sh_gt1 = 1;
        if (v != 0u && (i & 1)) sh_odd = 1;
    }
    __syncthreads();
    int fmode = sh_f32;

    for (int i = t; i < KH * DD; i += 256)
        Wf[i] = fmode ? ((const float*)W)[i] : bflo((uint32_t)wb[i]);
    for (int i = t; i < DD; i += 256) {
        bf[i] = fmode ? ((const float*)bias)[i] : bflo((uint32_t)((const uint16_t*)bias)[i]);
        float gv = fmode ? ((const float*)g)[i]  : bflo((uint32_t)((const uint16_t*)g)[i]);
        float sv = fmode ? ((const float*)sg)[i] : bflo((uint32_t)((const uint16_t*)sg)[i]);
        vf[i] = gv - sv;
    }
    if (t == 0) {
        hdr[0] = (uint32_t)sh_i32;
        hdr[1] = sh_gt1 ? 2u : (sh_odd ? 1u : 0u);
        hdr[2] = (uint32_t)fmode;
        hdr[3] = 0xFFFFFFFFu;
        hdr[4] = 0u;
        hdr[5] = 0u;
        hdr[6] = 0u;
    }
}

__device__ __forceinline__ void loadrow(const char* __restrict__ p, int fmode, float* h) {
    if (fmode) {
        const float4* q = (const float4*)p;
        #pragma unroll
        for (int t = 0; t < 8; ++t) {
            float4 u = q[t];
            h[t * 4 + 0] = u.x; h[t * 4 + 1] = u.y; h[t * 4 + 2] = u.z; h[t * 4 + 3] = u.w;
        }
    } else {
        const uint4* q = (const uint4*)p;
        #pragma unroll
        for (int t = 0; t < 4; ++t) {
            uint4 u = q[t];
            h[t * 8 + 0] = bflo(u.x); h[t * 8 + 1] = bfhi(u.x);
            h[t * 8 + 2] = bflo(u.y); h[t * 8 + 3] = bfhi(u.y);
            h[t * 8 + 4] = bflo(u.z); h[t * 8 + 5] = bfhi(u.z);
            h[t * 8 + 6] = bflo(u.w); h[t * 8 + 7] = bfhi(u.w);
        }
    }
}

__device__ __forceinline__ bool fetch_sel(const char* sel, int mode, int e) {
    if (mode == 2) return ((const uint8_t*)sel)[e] != 0;
    if (mode == 1) return ((const int*)sel)[e] != 0;
    return ((const long long*)sel)[e] != 0;
}

__device__ __forceinline__ void sp_store(float* __restrict__ ws_sp, void* __restrict__ out,
                                         int use_ws, int fmode, int e, float v) {
    if (use_ws) ws_sp[e] = v;
    else if (fmode) ((float*)out)[e] = v;
    else ((uint16_t*)out)[e] = f2bf(v);
}
__device__ __forceinline__ float sp_load(const float* __restrict__ ws_sp, const void* __restrict__ out,
                                         int use_ws, int fmode, int e) {
    if (use_ws) return ws_sp[e];
    if (fmode) return ((const float*)out)[e];
    return bflo((uint32_t)((const uint16_t*)out)[e]);
}

__global__ __launch_bounds__(256) void k_pass1(
    const char* __restrict__ node, const char* __restrict__ edgep,
    const char* __restrict__ ei, const char* __restrict__ sel,
    uint32_t* __restrict__ hdr, const float* __restrict__ Wf,
    const float* __restrict__ bf, const float* __restrict__ vf,
    float* __restrict__ ws_sp, void* __restrict__ out,
    int use_ws, int E, int N) {
    const int idx_mode = (int)hdr[0];
    const int sel_mode = (int)hdr[1];
    const int fmode    = (int)hdr[2];

    int e = blockIdx.x * 256 + threadIdx.x;
    bool valid = e < E;
    int ec = valid ? e : E - 1;

    long long si, di;
    if (idx_mode) { si = ((const int*)ei)[ec]; di = ((const int*)ei)[E + ec]; }
    else          { si = ((const long long*)ei)[ec]; di = ((const long long*)ei)[(size_t)E + ec]; }
    int s0 = (int)si; s0 = s0 < 0 ? 0 : (s0 >= N ? N - 1 : s0);
    int d0 = (int)di; d0 = d0 < 0 ? 0 : (d0 >= N ? N - 1 : d0);

    size_t rb = fmode ? 128 : 64;
    const char* p0 = node  + (size_t)s0 * rb;
    const char* p1 = node  + (size_t)d0 * rb;
    const char* p2 = edgep + (size_t)ec * rb;

    // acc init from bias (scalar-loaded, wave-uniform)
    float acc[DD];
    {
        vf16 b0, b1;
        wload(bf, b0, b1);
        #pragma unroll
        for (int j = 0; j < 16; ++j) { acc[j] = b0[j]; acc[16 + j] = b1[j]; }
    }

    float hh[32], hn[32];
    loadrow(p0, fmode, hh);

    #pragma unroll 1
    for (int r = 0; r < 3; ++r) {
        if (r < 2) {
            const char* pn = (r == 0) ? p1 : p2;
            loadrow(pn, fmode, hn);
        }
        const float* wp = Wf + r * 32 * DD;
        #pragma unroll
        for (int k = 0; k < 32; ++k) {
            vf16 w0, w1;
            wload(wp + k * DD, w0, w1);   // W row k into SGPRs
            float hk = hh[k];
            #pragma unroll
            for (int j = 0; j < 16; ++j) {
                acc[j]      = fmaf(hk, w0[j], acc[j]);
                acc[16 + j] = fmaf(hk, w1[j], acc[16 + j]);
            }
        }
        if (r < 2) {
            #pragma unroll
            for (int k = 0; k < 32; ++k) hh[k] = hn[k];
        }
    }

    float sp = 0.f;
    {
        vf16 v0, v1;
        wload(vf, v0, v1);
        #pragma unroll
        for (int j = 0; j < 16; ++j) {
            float a = acc[j];
            float act = a > 0.f ? a : (__expf(a) - 1.f);
            sp = fmaf(act, v0[j], sp);
            float a2 = acc[16 + j];
            float act2 = a2 > 0.f ? a2 : (__expf(a2) - 1.f);
            sp = fmaf(act2, v1[j], sp);
        }
    }

    bool selv = true;
    if (valid) {
        sp_store(ws_sp, out, use_ws, fmode, e, sp);
        selv = fetch_sel(sel, sel_mode, e);
    }

    float mn = valid ? sp : __builtin_inff();
    float mx = (valid && !selv) ? sp : -__builtin_inff();
    uint32_t c = (valid && !selv) ? 1u : 0u;
    #pragma unroll
    for (int o = 32; o >= 1; o >>= 1) {
        mn = fminf(mn, __shfl_xor(mn, o));
        mx = fmaxf(mx, __shfl_xor(mx, o));
        c += __shfl_xor(c, o);
    }
    __shared__ float smn[4], smx[4];
    __shared__ uint32_t sc[4];
    int wid = threadIdx.x >> 6, lane = threadIdx.x & 63;
    if (lane == 0) { smn[wid] = mn; smx[wid] = mx; sc[wid] = c; }
    __syncthreads();
    if (threadIdx.x == 0) {
        for (int w = 1; w < 4; ++w) { mn = fminf(mn, smn[w]); mx = fmaxf(mx, smx[w]); c += sc[w]; }
        atomicMin(&hdr[3], fkey(mn));
        atomicMax(&hdr[4], fkey(mx));
        if (c) atomicAdd(&hdr[5], c);
    }
}

__global__ __launch_bounds__(256) void k_pass2(
    const char* __restrict__ sel, uint32_t* __restrict__ hdr,
    const float* __restrict__ ws_sp, const void* __restrict__ out,
    int use_ws, int E) {
    int e = blockIdx.x * 256 + threadIdx.x;
    int sel_mode = (int)hdr[1], fmode = (int)hdr[2];
    float mn = funkey(hdr[3]);
    uint32_t cnt = hdr[5];
    float M = cnt ? funkey(hdr[4]) : mn;
    float p = 0.f;
    if (e < E) {
        float sp = sp_load(ws_sp, out, use_ws, fmode, e);
        bool selv = fetch_sel(sel, sel_mode, e);
        float masked = selv ? mn : sp;
        p = __expf((masked - M) * 2.0f);
    }
    #pragma unroll
    for (int o = 32; o >= 1; o >>= 1) p += __shfl_xor(p, o);
    __shared__ float sps[4];
    int wid = threadIdx.x >> 6, lane = threadIdx.x & 63;
    if (lane == 0) sps[wid] = p;
    __syncthreads();
    if (threadIdx.x == 0) {
        p += sps[1] + sps[2] + sps[3];
        atomicAdd((float*)&hdr[6], p);
    }
}

__global__ __launch_bounds__(256) void k_pass3(
    const char* __restrict__ sel, const uint32_t* __restrict__ hdr,
    const float* __restrict__ ws_sp, void* __restrict__ out,
    int use_ws, int E) {
    int e = blockIdx.x * 256 + threadIdx.x;
    if (e >= E) return;
    int sel_mode = (int)hdr[1], fmode = (int)hdr[2];
    float mn = funkey(hdr[3]);
    uint32_t cnt = hdr[5];
    float M = cnt ? funkey(hdr[4]) : mn;
    float S = __uint_as_float(hdr[6]);
    float sp = sp_load(ws_sp, out, use_ws, fmode, e);
    bool selv = fetch_sel(sel, sel_mode, e);
    float masked = selv ? mn : sp;
    float r = __expf((masked - M) * 2.0f) / S;
    if (fmode) ((float*)out)[e] = r;
    else       ((uint16_t*)out)[e] = f2bf(r);
}

extern "C" void kernel_launch(void* const* d_in, const int* in_sizes, int n_in,
                              void* d_out, int out_size, void* d_ws, size_t ws_size,
                              hipStream_t stream) {
    int N = in_sizes[0] / DD;
    int E = in_sizes[1] / DD;
    const void* node = d_in[0];
    const void* edge = d_in[1];
    const void* g    = d_in[2];
    const void* sg   = d_in[3];
    const void* W    = d_in[4];
    const void* bias = d_in[5];
    const void* ei   = d_in[6];
    const void* sel  = d_in[7];

    uint8_t* ws = (uint8_t*)d_ws;
    uint32_t* hdr = (uint32_t*)ws;
    float* Wf = (float*)(ws + 256);
    float* bf = (float*)(ws + 256 + 12288);
    float* vf = (float*)(ws + 256 + 12288 + 128);
    float* sp_arr = (float*)(ws + 16384);
    int use_ws = (ws_size >= (size_t)16384 + (size_t)E * sizeof(float)) ? 1 : 0;

    int grid = (E + 255) / 256;
    k_init<<<1, 256, 0, stream>>>(W, bias, g, sg, ei, sel, hdr, Wf, bf, vf, E, N);
    k_pass1<<<grid, 256, 0, stream>>>((const char*)node, (const char*)edge, (const char*)ei,
                                      (const char*)sel, hdr, Wf, bf, vf, sp_arr, d_out,
                                      use_ws, E, N);
    k_pass2<<<grid, 256, 0, stream>>>((const char*)sel, hdr, sp_arr, d_out, use_ws, E);
    k_pass3<<<grid, 256, 0, stream>>>((const char*)sel, hdr, sp_arr, d_out, use_ws, E);
}